// Round 1
// baseline (2568.048 us; speedup 1.0000x reference)
//
#include <hip/hip_runtime.h>
#include <hip/hip_bf16.h>

// Problem: out[b,s,o] = sum_i x[b,s,i] * (w[o,i] * scale[o/128, i/128])
// M = B*S = 4096, N = OUT = 18432, K = IN = 7168.
// Strategy: dequant w -> bf16 and convert x -> bf16 (threshold 0.59 permits
// bf16 compute; est. absmax err ~0.15), then m97-style bf16 MFMA GEMM
// (128x128 tile, BK=32, global_load_lds width 16, B^T layout).

#define M_DIM 4096
#define N_DIM 18432
#define K_DIM 7168
#define SCALE_COLS 56   // K/128
#define BM 128
#define BN 128
#define BK 32
#define GROUP_M 8

typedef unsigned short u16;
typedef short short8 __attribute__((ext_vector_type(8)));
typedef float floatx4 __attribute__((ext_vector_type(4)));
typedef float floatx4v __attribute__((ext_vector_type(4)));
typedef unsigned short ushortx8 __attribute__((ext_vector_type(8)));

typedef __attribute__((address_space(1))) unsigned int glb_uint;
typedef __attribute__((address_space(3))) unsigned int lds_uint;

__device__ __forceinline__ void async_copy16(const void* g, void* l) {
    __builtin_amdgcn_global_load_lds((glb_uint*)(g), (lds_uint*)(l), 16, 0, 0);
}

__device__ __forceinline__ u16 f32_to_bf16_rne(float f) {
    union { float f; unsigned int u; } v; v.f = f;
    unsigned int u = v.u;
    u += 0x7fffu + ((u >> 16) & 1u);   // round to nearest even
    return (u16)(u >> 16);
}

// ---------------------------------------------------------------------------
// x (fp32) -> bf16, 8 elements per thread. Grid covers M*K/8 exactly.
__global__ __launch_bounds__(256) void cvt_x_kernel(
    const float* __restrict__ x, ushortx8* __restrict__ xb)
{
    size_t idx = (size_t)blockIdx.x * 256 + threadIdx.x;   // chunk of 8 floats
    const floatx4* px = (const floatx4*)(x) + idx * 2;
    floatx4 f0 = px[0], f1 = px[1];
    ushortx8 r;
    r[0] = f32_to_bf16_rne(f0[0]); r[1] = f32_to_bf16_rne(f0[1]);
    r[2] = f32_to_bf16_rne(f0[2]); r[3] = f32_to_bf16_rne(f0[3]);
    r[4] = f32_to_bf16_rne(f1[0]); r[5] = f32_to_bf16_rne(f1[1]);
    r[6] = f32_to_bf16_rne(f1[2]); r[7] = f32_to_bf16_rne(f1[3]);
    xb[idx] = r;
}

// ---------------------------------------------------------------------------
// w (fp32) * scale -> bf16, 8 elements (along i) per thread. N*K/8 exact.
__global__ __launch_bounds__(256) void dequant_w_kernel(
    const float* __restrict__ w, const float* __restrict__ scale,
    ushortx8* __restrict__ wb)
{
    size_t idx = (size_t)blockIdx.x * 256 + threadIdx.x;   // chunk of 8 floats
    int i8 = (int)(idx % (K_DIM / 8));   // 0..895, element i = i8*8
    int o  = (int)(idx / (K_DIM / 8));
    float s = scale[(o >> 7) * SCALE_COLS + (i8 >> 4)];    // i/128 == i8/16
    const floatx4* pw = (const floatx4*)(w) + idx * 2;
    floatx4 f0 = pw[0], f1 = pw[1];
    ushortx8 r;
    r[0] = f32_to_bf16_rne(f0[0] * s); r[1] = f32_to_bf16_rne(f0[1] * s);
    r[2] = f32_to_bf16_rne(f0[2] * s); r[3] = f32_to_bf16_rne(f0[3] * s);
    r[4] = f32_to_bf16_rne(f1[0] * s); r[5] = f32_to_bf16_rne(f1[1] * s);
    r[6] = f32_to_bf16_rne(f1[2] * s); r[7] = f32_to_bf16_rne(f1[3] * s);
    wb[idx] = r;
}

// ---------------------------------------------------------------------------
// bf16 GEMM, C[m][n] = sum_k A[m][k] * Bt[n][k].  A:[M][K], Bt:[N][K] bf16,
// C:[M][N] fp32.  128x128 block tile, BK=32, 256 threads = 4 waves in 2x2,
// each wave a 64x64 tile = 4x4 mfma_f32_16x16x32_bf16.
__global__ __launch_bounds__(256) void gemm_bf16_bt(
    const u16* __restrict__ A, const u16* __restrict__ B,
    float* __restrict__ C)
{
    __shared__ u16 sA[BM * BK];   // 8 KB, row-major [128][32], NO padding
    __shared__ u16 sB[BN * BK];   // (global_load_lds requires contiguous)

    const int tid  = threadIdx.x;
    const int lane = tid & 63;
    const int wave = tid >> 6;
    const int quad = lane >> 4;
    const int l15  = lane & 15;
    const int wy   = wave >> 1;   // 0..1
    const int wx   = wave & 1;    // 0..1

    // GROUP_M block swizzle: consecutive blocks iterate m-tiles fastest so a
    // concurrent window (~768 blocks) shares B panels (B is 264 MB total).
    const int ntiles = N_DIM / BN;            // 144
    int gid   = blockIdx.x;
    int chunk = gid / (GROUP_M * ntiles);
    int rem   = gid % (GROUP_M * ntiles);
    int mt = chunk * GROUP_M + (rem % GROUP_M);
    int nt = rem / GROUP_M;
    const int m0 = mt * BM;
    const int n0 = nt * BN;

    // Staging addressing: each thread moves 16 B per instruction.
    // 4 threads per 64 B row; 256 threads cover 64 rows per pass; 2 passes.
    const int srow = tid >> 2;                // 0..63
    const int scol = (tid & 3) * 16;          // byte offset within row
    const char* gA = (const char*)(A + (size_t)(m0 + srow) * K_DIM) + scol;
    const char* gB = (const char*)(B + (size_t)(n0 + srow) * K_DIM) + scol;
    const size_t rowskip = (size_t)64 * K_DIM * 2;   // +64 rows, bytes
    char* sAb = (char*)sA;
    char* sBb = (char*)sB;

    floatx4 acc[4][4];
#pragma unroll
    for (int r = 0; r < 4; ++r)
#pragma unroll
        for (int c = 0; c < 4; ++c)
            acc[r][c] = (floatx4)0.0f;

    for (int k0 = 0; k0 < K_DIM; k0 += BK) {
        const char* ga = gA + (size_t)k0 * 2;
        const char* gb = gB + (size_t)k0 * 2;
        // A tile: 8 KB = 2 instructions/thread; LDS dest = wavebase + lane*16
        async_copy16(ga,            sAb + wave * 1024);
        async_copy16(ga + rowskip,  sAb + 4096 + wave * 1024);
        // B tile
        async_copy16(gb,            sBb + wave * 1024);
        async_copy16(gb + rowskip,  sBb + 4096 + wave * 1024);

        __syncthreads();   // compiler emits s_waitcnt vmcnt(0) before barrier

        short8 af[4], bf[4];
#pragma unroll
        for (int r = 0; r < 4; ++r)
            af[r] = *(const short8*)(sA + (wy * 64 + r * 16 + l15) * BK + quad * 8);
#pragma unroll
        for (int c = 0; c < 4; ++c)
            bf[c] = *(const short8*)(sB + (wx * 64 + c * 16 + l15) * BK + quad * 8);

#pragma unroll
        for (int r = 0; r < 4; ++r)
#pragma unroll
            for (int c = 0; c < 4; ++c)
                acc[r][c] = __builtin_amdgcn_mfma_f32_16x16x32_bf16(
                    af[r], bf[c], acc[r][c], 0, 0, 0);

        __syncthreads();   // before next stage overwrites LDS
    }

    // Epilogue: C/D layout col=lane&15, row=quad*4+reg.
#pragma unroll
    for (int r = 0; r < 4; ++r) {
#pragma unroll
        for (int c = 0; c < 4; ++c) {
            int n = n0 + wx * 64 + c * 16 + l15;
#pragma unroll
            for (int i = 0; i < 4; ++i) {
                int m = m0 + wy * 64 + r * 16 + quad * 4 + i;
                C[(size_t)m * N_DIM + n] = acc[r][c][i];
            }
        }
    }
}

// ---------------------------------------------------------------------------
// Fallback (if workspace too small): fp32 LDS-tiled GEMM w/ inline dequant.
// 64x64 tile, BK=16, 256 threads, 4x4 outputs/thread. Correct but slow.
__global__ __launch_bounds__(256) void fallback_gemm(
    const float* __restrict__ A, const float* __restrict__ Bw,
    const float* __restrict__ scale, float* __restrict__ C)
{
    __shared__ float sA[64][17];
    __shared__ float sB[64][17];
    const int tid = threadIdx.x;
    const int tx = tid & 15, ty = tid >> 4;
    const int n0 = blockIdx.x * 64;
    const int m0 = blockIdx.y * 64;
    const int lrow = tid >> 2;
    const int lk   = (tid & 3) * 4;
    float acc[4][4] = {};
    for (int k0 = 0; k0 < K_DIM; k0 += 16) {
        float4 a = *(const float4*)(A + (size_t)(m0 + lrow) * K_DIM + k0 + lk);
        float s = scale[((n0 + lrow) >> 7) * SCALE_COLS + ((k0 + lk) >> 7)];
        float4 b = *(const float4*)(Bw + (size_t)(n0 + lrow) * K_DIM + k0 + lk);
        sA[lrow][lk + 0] = a.x; sA[lrow][lk + 1] = a.y;
        sA[lrow][lk + 2] = a.z; sA[lrow][lk + 3] = a.w;
        sB[lrow][lk + 0] = b.x * s; sB[lrow][lk + 1] = b.y * s;
        sB[lrow][lk + 2] = b.z * s; sB[lrow][lk + 3] = b.w * s;
        __syncthreads();
#pragma unroll
        for (int kk = 0; kk < 16; ++kk) {
            float av[4], bv[4];
#pragma unroll
            for (int i = 0; i < 4; ++i) av[i] = sA[ty * 4 + i][kk];
#pragma unroll
            for (int j = 0; j < 4; ++j) bv[j] = sB[tx * 4 + j][kk];
#pragma unroll
            for (int i = 0; i < 4; ++i)
#pragma unroll
                for (int j = 0; j < 4; ++j) acc[i][j] += av[i] * bv[j];
        }
        __syncthreads();
    }
#pragma unroll
    for (int i = 0; i < 4; ++i)
#pragma unroll
        for (int j = 0; j < 4; ++j)
            C[(size_t)(m0 + ty * 4 + i) * N_DIM + n0 + tx * 4 + j] = acc[i][j];
}

// ---------------------------------------------------------------------------
extern "C" void kernel_launch(void* const* d_in, const int* in_sizes, int n_in,
                              void* d_out, int out_size, void* d_ws, size_t ws_size,
                              hipStream_t stream) {
    const float* x     = (const float*)d_in[0];
    const float* w     = (const float*)d_in[1];
    const float* scale = (const float*)d_in[2];
    float* out = (float*)d_out;

    const size_t wb_bytes = (size_t)N_DIM * K_DIM * 2;   // 264 MB
    const size_t xb_bytes = (size_t)M_DIM * K_DIM * 2;   //  59 MB
    if (ws_size >= wb_bytes + xb_bytes) {
        u16* wb = (u16*)d_ws;
        u16* xb = (u16*)((char*)d_ws + wb_bytes);
        dequant_w_kernel<<<dim3((N_DIM / 8) * (K_DIM / 8) / 256 * 8 / 8 * 8 / 8 * 8), dim3(256), 0, stream>>>(
            w, scale, (ushortx8*)wb);
        // grid above simplifies to N*K/8/256 = 64512; keep explicit:
        // (launch again is avoided: compute exact)
        cvt_x_kernel<<<dim3((M_DIM * K_DIM / 8) / 256), dim3(256), 0, stream>>>(
            x, (ushortx8*)xb);
        gemm_bf16_bt<<<dim3((M_DIM / BM) * (N_DIM / BN)), dim3(256), 0, stream>>>(
            xb, wb, out);
    } else {
        fallback_gemm<<<dim3(N_DIM / 64, M_DIM / 64), dim3(256), 0, stream>>>(
            x, w, scale, out);
    }
}